// Round 4
// baseline (3008.239 us; speedup 1.0000x reference)
//
#include <hip/hip_runtime.h>
#include <math.h>

#define C_   128
#define HU_  128
#define WU_  192
#define HD_  64
#define WD_  96
#define HWD_ (HD_ * WD_)

typedef unsigned short u16;
typedef __attribute__((ext_vector_type(8))) short s8v;   // 8 bf16 = 4 VGPRs
typedef __attribute__((ext_vector_type(4))) float f4v;   // MFMA C/D

// workspace layout (u16 units)
#define OFF_Q  0        // 2 layers x 16384
#define OFF_K  32768
#define OFF_V  65536
#define OFF_O  98304
#define OFF_F1 131072   // 2 layers x 65536
#define OFF_F2 262144
#define OFF_O1 393216   // 147456
// total 540672 u16 = 1.06 MB of d_ws

__device__ __forceinline__ u16 f2bf(float f) {
    unsigned u = __float_as_uint(f);
    unsigned r = (u + 0x7FFFu + ((u >> 16) & 1u)) >> 16;   // RNE
    return (u16)r;
}

__device__ __forceinline__ float gelu_tanh(float x) {
    float x3 = x * x * x;
    float t  = tanhf(0.7978845608028654f * (x + 0.044715f * x3));
    return 0.5f * x * (1.0f + t);
}
__device__ __forceinline__ float gelu_erf(float x) {
    return 0.5f * x * (1.0f + erff(x * 0.7071067811865476f));
}

// ---------------- weight swizzle prologue ----------------
// dst blob: frag (kt,nt): 64 lanes x 8 bf16; element j = W[kt*32+8*(lane>>4)+j][nt*16+(lane&15)]
__global__ void swz_kernel(const float* __restrict__ src, u16* __restrict__ dst,
                           int KT, int NT, int N) {
    int tid = blockIdx.x * 256 + threadIdx.x;
    if (tid >= KT * NT * 64) return;
    int lane = tid & 63, f = tid >> 6;
    int nt = f % NT, kt = f / NT;
    int row0 = kt * 32 + 8 * (lane >> 4);
    int col  = nt * 16 + (lane & 15);
    s8v o;
#pragma unroll
    for (int j = 0; j < 8; ++j)
        o[j] = (short)f2bf(src[(size_t)(row0 + j) * N + col]);
    *(s8v*)(dst + (size_t)tid * 8) = o;
}

// ---------------- main fused kernel ----------------
// 1 wave per block, 16 consecutive pixels (same hu row).
__global__ __launch_bounds__(64, 2) void fused_kernel(
    const float* __restrict__ fm, const float* __restrict__ fmu,
    const u16*  __restrict__ wsb,
    const float* __restrict__ ctx_g, const float* __restrict__ ctx_b,
    const float* __restrict__ qb, const float* __restrict__ kb,
    const float* __restrict__ vb, const float* __restrict__ ob,
    const float* __restrict__ f1b, const float* __restrict__ f2b,
    const float* __restrict__ o1b, const float* __restrict__ o2w,
    const float* __restrict__ o2b,
    float* __restrict__ out)
{
    const int lane = threadIdx.x;
    const int cidx = lane & 15, quad = lane >> 4;
    const int n0 = blockIdx.x * 16;
    const int b  = n0 / (HU_ * WU_);
    const int rem = n0 - b * (HU_ * WU_);
    const int hu  = rem / WU_;
    const int wu0 = rem - hu * WU_;
    const int ctx_base = b * C_ * HWD_;

    __shared__ u16  bufT[16 * 136];     // bf16 A-tile (row stride 272 B)
    __shared__ float bufQ[16 * 136];    // q f32 / xf f32 / o-tile (as u16)
    __shared__ float s_attn[16 * 16];   // [p][h*4+k2]
    __shared__ u16  sH[16 * 520];       // fc1 activations bf16 (row stride 1040 B)
    __shared__ float s_rs[64];

    u16* oT = (u16*)bufQ;

    // residual x in C-layout: row p = 4*quad+r, ch = 16*nt+cidx
    float xacc[8][4];
#pragma unroll
    for (int nt = 0; nt < 8; ++nt) {
        int ch = 16 * nt + cidx;
        const float* p = fmu + ((size_t)(b * C_ + ch) * HU_ + hu) * WU_ + wu0 + 4 * quad;
#pragma unroll
        for (int r = 0; r < 4; ++r) xacc[nt][r] = p[r];
    }

    const float slopes[4] = {0.451801007f, 0.204124145f, 0.092223264f, 0.041666668f};
    const int ry0 = min(hu >> 1, HD_ - 1);
    const int ry1 = min((hu >> 1) + 1, HD_ - 1);
    const float dyv0 = -(float)abs(hu - 2 * ry0);
    const float dyv1 = -(float)abs(hu - 2 * ry1);

#pragma unroll 1
    for (int ly = 0; ly < 2; ++ly) {
        const u16* Wq = wsb + OFF_Q  + ly * 16384;
        const u16* Wk = wsb + OFF_K  + ly * 16384;
        const u16* Wv = wsb + OFF_V  + ly * 16384;
        const u16* Wo = wsb + OFF_O  + ly * 16384;
        const u16* W1 = wsb + OFF_F1 + ly * 65536;
        const u16* W2 = wsb + OFF_F2 + ly * 65536;
        const float* gv  = ctx_g + ly * C_;
        const float* bv  = ctx_b + ly * C_;
        const float* qbv = qb + ly * C_;
        const float* kbv = kb + ly * C_;
        const float* vbv = vb + ly * C_;
        const float* obv = ob + ly * C_;
        const float* f1bv = f1b + ly * 512;
        const float* f2bv = f2b + ly * C_;

        // ---- xn = LN(x,1e-6) -> bufT ----
        {
            float mo[4], io[4];
#pragma unroll
            for (int r = 0; r < 4; ++r) {
                float s = 0.f, ss = 0.f;
#pragma unroll
                for (int nt = 0; nt < 8; ++nt) { float v = xacc[nt][r]; s += v; ss += v * v; }
#pragma unroll
                for (int m = 1; m <= 8; m <<= 1) { s += __shfl_xor(s, m, 64); ss += __shfl_xor(ss, m, 64); }
                float mn = s * (1.f / 128.f);
                float var = ss * (1.f / 128.f) - mn * mn;
                mo[r] = mn; io[r] = rsqrtf(var + 1e-6f);
            }
#pragma unroll
            for (int nt = 0; nt < 8; ++nt)
#pragma unroll
                for (int r = 0; r < 4; ++r)
                    bufT[(4 * quad + r) * 136 + 16 * nt + cidx] =
                        f2bf((xacc[nt][r] - mo[r]) * io[r]);
        }
        __syncthreads();

        // ---- q = xn @ Wq + qb -> bufQ (f32) ----
        {
            f4v qa[8];
#pragma unroll
            for (int nt = 0; nt < 8; ++nt) {
                float bvv = qbv[16 * nt + cidx];
                f4v t = {bvv, bvv, bvv, bvv}; qa[nt] = t;
            }
            for (int kt = 0; kt < 4; ++kt) {
                s8v a = *(const s8v*)(bufT + cidx * 136 + kt * 32 + 8 * quad);
#pragma unroll
                for (int nt = 0; nt < 8; ++nt) {
                    s8v w = *(const s8v*)(Wq + ((size_t)((kt * 8 + nt) * 64 + lane)) * 8);
                    qa[nt] = __builtin_amdgcn_mfma_f32_16x16x32_bf16(a, w, qa[nt], 0, 0, 0);
                }
            }
            __syncthreads();
#pragma unroll
            for (int nt = 0; nt < 8; ++nt)
#pragma unroll
                for (int r = 0; r < 4; ++r)
                    bufQ[(4 * quad + r) * 136 + 16 * nt + cidx] = qa[nt][r];
        }
        __syncthreads();

        // ---- k GEMM per M-tile, fused scores + softmax -> s_attn ----
#pragma unroll 1
        for (int mt = 0; mt < 4; ++mt) {
            // build cn tile (affine LN, eps 1e-5)
            {
                int p  = 4 * mt + (cidx >> 2);
                int k2 = cidx & 3;
                int ry = (k2 >> 1) ? ry1 : ry0;
                int rxv = min(((wu0 + p) >> 1) + (k2 & 1), WD_ - 1);
                const float* src = fm + ctx_base + ry * WD_ + rxv + (size_t)(32 * quad) * HWD_;
                float v[32];
#pragma unroll
                for (int j = 0; j < 32; ++j) v[j] = src[(size_t)j * HWD_];
                float s = 0.f, ss = 0.f;
#pragma unroll
                for (int j = 0; j < 32; ++j) { s += v[j]; ss += v[j] * v[j]; }
                s += __shfl_xor(s, 16, 64); ss += __shfl_xor(ss, 16, 64);
                s += __shfl_xor(s, 32, 64); ss += __shfl_xor(ss, 32, 64);
                float mn = s * (1.f / 128.f);
                float inv = rsqrtf(ss * (1.f / 128.f) - mn * mn + 1e-5f);
#pragma unroll
                for (int t4 = 0; t4 < 4; ++t4) {
                    float4 g4 = *(const float4*)&gv[32 * quad + 4 * t4 + ((t4 & 1) ? 0 : 0)];
                    float4 b4 = *(const float4*)&bv[32 * quad + 4 * t4];
                    float tv[4] = {((v[4*t4+0] - mn) * inv) * g4.x + b4.x,
                                   ((v[4*t4+1] - mn) * inv) * g4.y + b4.y,
                                   ((v[4*t4+2] - mn) * inv) * g4.z + b4.z,
                                   ((v[4*t4+3] - mn) * inv) * g4.w + b4.w};
                    // pack into tile (2 per b32 via u16 stores)
#pragma unroll
                    for (int e = 0; e < 4; ++e)
                        bufT[cidx * 136 + 32 * quad + 4 * t4 + e] = f2bf(tv[e]);
                }
            }
            __syncthreads();
            f4v ka[8];
#pragma unroll
            for (int nt = 0; nt < 8; ++nt) {
                float bvv = kbv[16 * nt + cidx];
                f4v t = {bvv, bvv, bvv, bvv}; ka[nt] = t;
            }
            for (int kt = 0; kt < 4; ++kt) {
                s8v a = *(const s8v*)(bufT + cidx * 136 + kt * 32 + 8 * quad);
#pragma unroll
                for (int nt = 0; nt < 8; ++nt) {
                    s8v w = *(const s8v*)(Wk + ((size_t)((kt * 8 + nt) * 64 + lane)) * 8);
                    ka[nt] = __builtin_amdgcn_mfma_f32_16x16x32_bf16(a, w, ka[nt], 0, 0, 0);
                }
            }
            // scores: lane holds k rows (p=4mt+quad, k2=r), ch 16nt+cidx
            float part[4][4];
#pragma unroll
            for (int h = 0; h < 4; ++h)
#pragma unroll
                for (int r = 0; r < 4; ++r) part[h][r] = 0.f;
#pragma unroll
            for (int nt = 0; nt < 8; ++nt) {
                float qv = bufQ[(4 * mt + quad) * 136 + 16 * nt + cidx];
                int h = nt >> 1;
#pragma unroll
                for (int r = 0; r < 4; ++r) part[h][r] = fmaf(qv, ka[nt][r], part[h][r]);
            }
#pragma unroll
            for (int h = 0; h < 4; ++h)
#pragma unroll
                for (int r = 0; r < 4; ++r) {
#pragma unroll
                    for (int m = 1; m <= 8; m <<= 1)
                        part[h][r] += __shfl_xor(part[h][r], m, 64);
                }
            {
                int pw = wu0 + 4 * mt + quad;
                float cd[4];
#pragma unroll
                for (int r = 0; r < 4; ++r) {
                    int rxv = min((pw >> 1) + (r & 1), WD_ - 1);
                    float dx = -(float)abs(pw - 2 * rxv);
                    cd[r] = ((r >> 1) ? dyv1 : dyv0) + dx;
                }
#pragma unroll
                for (int h = 0; h < 4; ++h) {
                    float sim[4];
#pragma unroll
                    for (int r = 0; r < 4; ++r)
                        sim[r] = part[h][r] * 0.17677669529663687f + slopes[h] * cd[r];
                    float mx = fmaxf(fmaxf(sim[0], sim[1]), fmaxf(sim[2], sim[3]));
                    float e0 = expf(sim[0] - mx), e1 = expf(sim[1] - mx);
                    float e2 = expf(sim[2] - mx), e3 = expf(sim[3] - mx);
                    float si = 1.f / (e0 + e1 + e2 + e3);
                    if (cidx == 0) {
                        float4 at = {e0 * si, e1 * si, e2 * si, e3 * si};
                        *(float4*)&s_attn[(4 * mt + quad) * 16 + 4 * h] = at;
                    }
                }
            }
            __syncthreads();
        }

        // ---- v GEMM per M-tile, fused o = attn@v -> oT (bf16 rows = pixels) ----
#pragma unroll 1
        for (int mt = 0; mt < 4; ++mt) {
            {
                int p  = 4 * mt + (cidx >> 2);
                int k2 = cidx & 3;
                int ry = (k2 >> 1) ? ry1 : ry0;
                int rxv = min(((wu0 + p) >> 1) + (k2 & 1), WD_ - 1);
                const float* src = fm + ctx_base + ry * WD_ + rxv + (size_t)(32 * quad) * HWD_;
                float v[32];
#pragma unroll
                for (int j = 0; j < 32; ++j) v[j] = src[(size_t)j * HWD_];
                float s = 0.f, ss = 0.f;
#pragma unroll
                for (int j = 0; j < 32; ++j) { s += v[j]; ss += v[j] * v[j]; }
                s += __shfl_xor(s, 16, 64); ss += __shfl_xor(ss, 16, 64);
                s += __shfl_xor(s, 32, 64); ss += __shfl_xor(ss, 32, 64);
                float mn = s * (1.f / 128.f);
                float inv = rsqrtf(ss * (1.f / 128.f) - mn * mn + 1e-5f);
#pragma unroll
                for (int t4 = 0; t4 < 4; ++t4) {
                    float4 g4 = *(const float4*)&gv[32 * quad + 4 * t4];
                    float4 b4 = *(const float4*)&bv[32 * quad + 4 * t4];
                    bufT[cidx * 136 + 32 * quad + 4 * t4 + 0] = f2bf(((v[4*t4+0] - mn) * inv) * g4.x + b4.x);
                    bufT[cidx * 136 + 32 * quad + 4 * t4 + 1] = f2bf(((v[4*t4+1] - mn) * inv) * g4.y + b4.y);
                    bufT[cidx * 136 + 32 * quad + 4 * t4 + 2] = f2bf(((v[4*t4+2] - mn) * inv) * g4.z + b4.z);
                    bufT[cidx * 136 + 32 * quad + 4 * t4 + 3] = f2bf(((v[4*t4+3] - mn) * inv) * g4.w + b4.w);
                }
            }
            __syncthreads();
            f4v va[8];
#pragma unroll
            for (int nt = 0; nt < 8; ++nt) {
                float bvv = vbv[16 * nt + cidx];
                f4v t = {bvv, bvv, bvv, bvv}; va[nt] = t;
            }
            for (int kt = 0; kt < 4; ++kt) {
                s8v a = *(const s8v*)(bufT + cidx * 136 + kt * 32 + 8 * quad);
#pragma unroll
                for (int nt = 0; nt < 8; ++nt) {
                    s8v w = *(const s8v*)(Wv + ((size_t)((kt * 8 + nt) * 64 + lane)) * 8);
                    va[nt] = __builtin_amdgcn_mfma_f32_16x16x32_bf16(a, w, va[nt], 0, 0, 0);
                }
            }
#pragma unroll
            for (int nt = 0; nt < 8; ++nt) {
                float4 at = *(float4*)&s_attn[(4 * mt + quad) * 16 + 4 * (nt >> 1)];
                float ov = at.x * va[nt][0] + at.y * va[nt][1] + at.z * va[nt][2] + at.w * va[nt][3];
                oT[(4 * mt + quad) * 136 + 16 * nt + cidx] = f2bf(ov);
            }
            __syncthreads();
        }

        // ---- x += o @ Wo + ob ----
        {
            f4v oa[8];
#pragma unroll
            for (int nt = 0; nt < 8; ++nt) {
                float bvv = obv[16 * nt + cidx];
                f4v t = {bvv, bvv, bvv, bvv}; oa[nt] = t;
            }
            for (int kt = 0; kt < 4; ++kt) {
                s8v a = *(const s8v*)(oT + cidx * 136 + kt * 32 + 8 * quad);
#pragma unroll
                for (int nt = 0; nt < 8; ++nt) {
                    s8v w = *(const s8v*)(Wo + ((size_t)((kt * 8 + nt) * 64 + lane)) * 8);
                    oa[nt] = __builtin_amdgcn_mfma_f32_16x16x32_bf16(a, w, oa[nt], 0, 0, 0);
                }
            }
#pragma unroll
            for (int nt = 0; nt < 8; ++nt)
#pragma unroll
                for (int r = 0; r < 4; ++r) xacc[nt][r] += oa[nt][r];
        }
        __syncthreads();

        // ---- hn = LN(x,1e-6) -> bufT ----
        {
            float mo[4], io[4];
#pragma unroll
            for (int r = 0; r < 4; ++r) {
                float s = 0.f, ss = 0.f;
#pragma unroll
                for (int nt = 0; nt < 8; ++nt) { float v = xacc[nt][r]; s += v; ss += v * v; }
#pragma unroll
                for (int m = 1; m <= 8; m <<= 1) { s += __shfl_xor(s, m, 64); ss += __shfl_xor(ss, m, 64); }
                float mn = s * (1.f / 128.f);
                mo[r] = mn; io[r] = rsqrtf(ss * (1.f / 128.f) - mn * mn + 1e-6f);
            }
#pragma unroll
            for (int nt = 0; nt < 8; ++nt)
#pragma unroll
                for (int r = 0; r < 4; ++r)
                    bufT[(4 * quad + r) * 136 + 16 * nt + cidx] =
                        f2bf((xacc[nt][r] - mo[r]) * io[r]);
        }
        __syncthreads();

        // ---- fc1 (128->512) + gelu_tanh -> sH ----
#pragma unroll 1
        for (int half = 0; half < 2; ++half) {
            f4v fa[16];
#pragma unroll
            for (int nt = 0; nt < 16; ++nt) {
                float bvv = f1bv[16 * (half * 16 + nt) + cidx];
                f4v t = {bvv, bvv, bvv, bvv}; fa[nt] = t;
            }
            for (int kt = 0; kt < 4; ++kt) {
                s8v a = *(const s8v*)(bufT + cidx * 136 + kt * 32 + 8 * quad);
#pragma unroll
                for (int nt = 0; nt < 16; ++nt) {
                    int ntg = half * 16 + nt;
                    s8v w = *(const s8v*)(W1 + ((size_t)((kt * 32 + ntg) * 64 + lane)) * 8);
                    fa[nt] = __builtin_amdgcn_mfma_f32_16x16x32_bf16(a, w, fa[nt], 0, 0, 0);
                }
            }
#pragma unroll
            for (int nt = 0; nt < 16; ++nt)
#pragma unroll
                for (int r = 0; r < 4; ++r)
                    sH[(4 * quad + r) * 520 + 16 * (half * 16 + nt) + cidx] =
                        f2bf(gelu_tanh(fa[nt][r]));
        }
        __syncthreads();

        // ---- x += act @ W2 + f2b ----
        {
            f4v ga[8];
#pragma unroll
            for (int nt = 0; nt < 8; ++nt) {
                float bvv = f2bv[16 * nt + cidx];
                f4v t = {bvv, bvv, bvv, bvv}; ga[nt] = t;
            }
            for (int kt = 0; kt < 16; ++kt) {
                s8v a = *(const s8v*)(sH + cidx * 520 + kt * 32 + 8 * quad);
#pragma unroll
                for (int nt = 0; nt < 8; ++nt) {
                    s8v w = *(const s8v*)(W2 + ((size_t)((kt * 8 + nt) * 64 + lane)) * 8);
                    ga[nt] = __builtin_amdgcn_mfma_f32_16x16x32_bf16(a, w, ga[nt], 0, 0, 0);
                }
            }
#pragma unroll
            for (int nt = 0; nt < 8; ++nt)
#pragma unroll
                for (int r = 0; r < 4; ++r) xacc[nt][r] += ga[nt][r];
        }
        __syncthreads();
    } // layer loop

    // ---- head: xf = LN(x,1e-6) -> bufQ (f32) ----
    {
        float mo[4], io[4];
#pragma unroll
        for (int r = 0; r < 4; ++r) {
            float s = 0.f, ss = 0.f;
#pragma unroll
            for (int nt = 0; nt < 8; ++nt) { float v = xacc[nt][r]; s += v; ss += v * v; }
#pragma unroll
            for (int m = 1; m <= 8; m <<= 1) { s += __shfl_xor(s, m, 64); ss += __shfl_xor(ss, m, 64); }
            float mn = s * (1.f / 128.f);
            mo[r] = mn; io[r] = rsqrtf(ss * (1.f / 128.f) - mn * mn + 1e-6f);
        }
        __syncthreads();
#pragma unroll
        for (int nt = 0; nt < 8; ++nt)
#pragma unroll
            for (int r = 0; r < 4; ++r)
                bufQ[(4 * quad + r) * 136 + 16 * nt + cidx] = (xacc[nt][r] - mo[r]) * io[r];
    }
    __syncthreads();

    const u16* W1h = wsb + OFF_O1;
#pragma unroll 1
    for (int mt = 0; mt < 4; ++mt) {
        f4v ha[24];
#pragma unroll
        for (int nt = 0; nt < 24; ++nt) {
            float bvv = o1b[16 * nt + cidx];
            f4v t = {bvv, bvv, bvv, bvv}; ha[nt] = t;
        }
        float cfv[32];

        // seg0: rows = xf[p]
        {
            int p = 4 * mt + (cidx >> 2);
#pragma unroll
            for (int t4 = 0; t4 < 8; ++t4) {
                float4 xv = *(float4*)&bufQ[p * 136 + 32 * quad + 4 * t4];
                bufT[cidx * 136 + 32 * quad + 4 * t4 + 0] = f2bf(xv.x);
                bufT[cidx * 136 + 32 * quad + 4 * t4 + 1] = f2bf(xv.y);
                bufT[cidx * 136 + 32 * quad + 4 * t4 + 2] = f2bf(xv.z);
                bufT[cidx * 136 + 32 * quad + 4 * t4 + 3] = f2bf(xv.w);
            }
        }
        __syncthreads();
        for (int kt = 0; kt < 4; ++kt) {
            s8v a = *(const s8v*)(bufT + cidx * 136 + kt * 32 + 8 * quad);
#pragma unroll
            for (int nt = 0; nt < 24; ++nt) {
                s8v w = *(const s8v*)(W1h + ((size_t)((kt * 24 + nt) * 64 + lane)) * 8);
                ha[nt] = __builtin_amdgcn_mfma_f32_16x16x32_bf16(a, w, ha[nt], 0, 0, 0);
            }
        }
        __syncthreads();

        // seg1: rows = cf = LN(ctx,1e-6)
        {
            int p  = 4 * mt + (cidx >> 2);
            int k2 = cidx & 3;
            int ry = (k2 >> 1) ? ry1 : ry0;
            int rxv = min(((wu0 + p) >> 1) + (k2 & 1), WD_ - 1);
            const float* src = fm + ctx_base + ry * WD_ + rxv + (size_t)(32 * quad) * HWD_;
            float v[32];
#pragma unroll
            for (int j = 0; j < 32; ++j) v[j] = src[(size_t)j * HWD_];
            float s = 0.f, ss = 0.f;
#pragma unroll
            for (int j = 0; j < 32; ++j) { s += v[j]; ss += v[j] * v[j]; }
            s += __shfl_xor(s, 16, 64); ss += __shfl_xor(ss, 16, 64);
            s += __shfl_xor(s, 32, 64); ss += __shfl_xor(ss, 32, 64);
            float mn = s * (1.f / 128.f);
            float inv = rsqrtf(ss * (1.f / 128.f) - mn * mn + 1e-6f);
#pragma unroll
            for (int j = 0; j < 32; ++j) {
                cfv[j] = (v[j] - mn) * inv;
                bufT[cidx * 136 + 32 * quad + j] = f2bf(cfv[j]);
            }
        }
        __syncthreads();
        for (int kt = 0; kt < 4; ++kt) {
            s8v a = *(const s8v*)(bufT + cidx * 136 + kt * 32 + 8 * quad);
#pragma unroll
            for (int nt = 0; nt < 24; ++nt) {
                s8v w = *(const s8v*)(W1h + ((size_t)(((kt + 4) * 24 + nt) * 64 + lane)) * 8);
                ha[nt] = __builtin_amdgcn_mfma_f32_16x16x32_bf16(a, w, ha[nt], 0, 0, 0);
            }
        }
        __syncthreads();

        // seg2: rows = xf - cf
        {
            int p = 4 * mt + (cidx >> 2);
#pragma unroll
            for (int t4 = 0; t4 < 8; ++t4) {
                float4 xv = *(float4*)&bufQ[p * 136 + 32 * quad + 4 * t4];
                bufT[cidx * 136 + 32 * quad + 4 * t4 + 0] = f2bf(xv.x - cfv[4 * t4 + 0]);
                bufT[cidx * 136 + 32 * quad + 4 * t4 + 1] = f2bf(xv.y - cfv[4 * t4 + 1]);
                bufT[cidx * 136 + 32 * quad + 4 * t4 + 2] = f2bf(xv.z - cfv[4 * t4 + 2]);
                bufT[cidx * 136 + 32 * quad + 4 * t4 + 3] = f2bf(xv.w - cfv[4 * t4 + 3]);
            }
        }
        __syncthreads();
        for (int kt = 0; kt < 4; ++kt) {
            s8v a = *(const s8v*)(bufT + cidx * 136 + kt * 32 + 8 * quad);
#pragma unroll
            for (int nt = 0; nt < 24; ++nt) {
                s8v w = *(const s8v*)(W1h + ((size_t)(((kt + 8) * 24 + nt) * 64 + lane)) * 8);
                ha[nt] = __builtin_amdgcn_mfma_f32_16x16x32_bf16(a, w, ha[nt], 0, 0, 0);
            }
        }
        __syncthreads();

        // epilogue: gelu_erf, dot with out2_w, reduce over 16 lanes
        float part[4] = {0.f, 0.f, 0.f, 0.f};
#pragma unroll
        for (int nt = 0; nt < 24; ++nt) {
            float w2v = o2w[16 * nt + cidx];
#pragma unroll
            for (int r = 0; r < 4; ++r)
                part[r] = fmaf(gelu_erf(ha[nt][r]), w2v, part[r]);
        }
#pragma unroll
        for (int r = 0; r < 4; ++r) {
#pragma unroll
            for (int m = 1; m <= 8; m <<= 1) part[r] += __shfl_xor(part[r], m, 64);
            part[r] += o2b[0];
        }
        if (cidx == 0) {
            float4 t = {part[0], part[1], part[2], part[3]};
            *(float4*)&s_rs[16 * mt + 4 * quad] = t;
        }
    }
    __syncthreads();

    // final softmax over K2 + store
    if (lane < 16) {
        int p = lane;
        float4 vv = *(float4*)&s_rs[4 * p];
        float mx = fmaxf(fmaxf(vv.x, vv.y), fmaxf(vv.z, vv.w));
        float e0 = expf(vv.x - mx), e1 = expf(vv.y - mx);
        float e2 = expf(vv.z - mx), e3 = expf(vv.w - mx);
        float si = 1.f / (e0 + e1 + e2 + e3);
        size_t base = ((size_t)(b * 4) * HU_ + hu) * WU_ + wu0 + p;
        out[base]                          = e0 * si;
        out[base + (size_t)HU_ * WU_]      = e1 * si;
        out[base + (size_t)2 * HU_ * WU_]  = e2 * si;
        out[base + (size_t)3 * HU_ * WU_]  = e3 * si;
    }
}

extern "C" void kernel_launch(void* const* d_in, const int* in_sizes, int n_in,
                              void* d_out, int out_size, void* d_ws, size_t ws_size,
                              hipStream_t stream) {
    const float* feat_map    = (const float*)d_in[0];
    const float* feat_map_up = (const float*)d_in[1];
    const float* ctx_ln_b    = (const float*)d_in[2];
    const float* q_w  = (const float*)d_in[3];
    const float* q_b  = (const float*)d_in[4];
    const float* k_w  = (const float*)d_in[5];
    const float* k_b  = (const float*)d_in[6];
    const float* v_w  = (const float*)d_in[7];
    const float* v_b  = (const float*)d_in[8];
    const float* o_w  = (const float*)d_in[9];
    const float* o_b  = (const float*)d_in[10];
    const float* fc1_w = (const float*)d_in[11];
    const float* fc1_b = (const float*)d_in[12];
    const float* fc2_w = (const float*)d_in[13];
    const float* fc2_b = (const float*)d_in[14];
    const float* out1_w = (const float*)d_in[15];
    const float* out1_b = (const float*)d_in[16];
    const float* out2_w = (const float*)d_in[17];
    const float* out2_b = (const float*)d_in[18];
    const float* ctx_ln_g = (const float*)d_in[19];
    float* out = (float*)d_out;
    u16* ws = (u16*)d_ws;

    // weight swizzle prologue (bf16 b-frag blobs)
    for (int l = 0; l < 2; ++l) {
        swz_kernel<<<8, 256, 0, stream>>>(q_w + l * 16384, ws + OFF_Q + l * 16384, 4, 8, 128);
        swz_kernel<<<8, 256, 0, stream>>>(k_w + l * 16384, ws + OFF_K + l * 16384, 4, 8, 128);
        swz_kernel<<<8, 256, 0, stream>>>(v_w + l * 16384, ws + OFF_V + l * 16384, 4, 8, 128);
        swz_kernel<<<8, 256, 0, stream>>>(o_w + l * 16384, ws + OFF_O + l * 16384, 4, 8, 128);
        swz_kernel<<<32, 256, 0, stream>>>(fc1_w + l * 65536, ws + OFF_F1 + l * 65536, 4, 32, 512);
        swz_kernel<<<32, 256, 0, stream>>>(fc2_w + l * 65536, ws + OFF_F2 + l * 65536, 16, 8, 128);
    }
    swz_kernel<<<72, 256, 0, stream>>>(out1_w, ws + OFF_O1, 12, 24, 384);

    fused_kernel<<<3072, 64, 0, stream>>>(
        feat_map, feat_map_up, ws, ctx_ln_g, ctx_ln_b,
        q_b, k_b, v_b, o_b, fc1_b, fc2_b,
        out1_b, out2_w, out2_b, out);
}

// Round 5
// 666.327 us; speedup vs baseline: 4.5147x; 4.5147x over previous
//
#include <hip/hip_runtime.h>
#include <math.h>

#define C_   128
#define HU_  128
#define WU_  192
#define HD_  64
#define WD_  96
#define HWD_ (HD_ * WD_)

typedef unsigned short u16;
typedef __attribute__((ext_vector_type(8))) short s8v;   // 8 bf16 = 4 VGPRs
typedef __attribute__((ext_vector_type(4))) float f4v;   // MFMA C/D

// ---- workspace layout (u16 units) ----
#define OFF_Q   0        // 2 layers x 16384
#define OFF_K   32768
#define OFF_V   65536
#define OFF_O   98304
#define OFF_F1  131072   // 2 layers x 65536
#define OFF_F2  262144
#define OFF_O1  393216   // 147456
#define OFF_NRM 540672   // normalized ctx bf16: (B,HD,WD,C) = 1572864 u16
// total 2113536 u16 = 4.2 MB

#define SLOT 2176        // u16 per LDS tile slot (16 rows x 136)

__device__ __forceinline__ u16 f2bf(float f) {
    unsigned u = __float_as_uint(f);
    unsigned r = (u + 0x7FFFu + ((u >> 16) & 1u)) >> 16;   // RNE
    return (u16)r;
}
__device__ __forceinline__ float bfu(u16 h) { return __uint_as_float(((unsigned)h) << 16); }

__device__ __forceinline__ float gelu_tanh(float x) {
    float x3 = x * x * x;
    float t  = tanhf(0.7978845608028654f * (x + 0.044715f * x3));
    return 0.5f * x * (1.0f + t);
}
__device__ __forceinline__ float gelu_erf(float x) {
    return 0.5f * x * (1.0f + erff(x * 0.7071067811865476f));
}

// ---------------- prologue 1: weight swizzle ----------------
// frag (kt,nt): 64 lanes x 8 bf16; elem j = W[kt*32+8*(lane>>4)+j][nt*16+(lane&15)]
__global__ void swz_kernel(const float* __restrict__ src, u16* __restrict__ dst,
                           int KT, int NT, int N) {
    int tid = blockIdx.x * 256 + threadIdx.x;
    if (tid >= KT * NT * 64) return;
    int lane = tid & 63, f = tid >> 6;
    int nt = f % NT, kt = f / NT;
    int row0 = kt * 32 + 8 * (lane >> 4);
    int col  = nt * 16 + (lane & 15);
    s8v o;
#pragma unroll
    for (int j = 0; j < 8; ++j)
        o[j] = (short)f2bf(src[(size_t)(row0 + j) * N + col]);
    *(s8v*)(dst + (size_t)tid * 8) = o;
}

// ---------------- prologue 2: normalize feat_map per down-pixel ----------------
// out: nrm[((b*HD+y)*WD+x)*128 + c] = LN(feat_map[b,:,y,x]) (eps 1e-5), bf16
__global__ __launch_bounds__(256) void norm_kernel(const float* __restrict__ fm,
                                                   u16* __restrict__ dst) {
    int row = blockIdx.x;          // b*HD + y, 0..127
    int b = row >> 6, y = row & 63;
    __shared__ float tile[128 * 97];
    __shared__ float smean[96], srst[96];
    for (int idx = threadIdx.x; idx < 128 * 96; idx += 256) {
        int c = idx / 96, w = idx - c * 96;
        tile[c * 97 + w] = fm[(((size_t)b * 128 + c) * 64 + y) * 96 + w];
    }
    __syncthreads();
    if (threadIdx.x < 96) {
        int w = threadIdx.x;
        float s = 0.f, ss = 0.f;
        for (int c = 0; c < 128; ++c) { float v = tile[c * 97 + w]; s += v; ss += v * v; }
        float mn = s * (1.f / 128.f);
        smean[w] = mn;
        srst[w]  = rsqrtf(ss * (1.f / 128.f) - mn * mn + 1e-5f);
    }
    __syncthreads();
    for (int idx = threadIdx.x; idx < 128 * 96; idx += 256) {
        int w = idx >> 7, c = idx & 127;
        dst[((size_t)row * 96 + w) * 128 + c] = f2bf((tile[c * 97 + w] - smean[w]) * srst[w]);
    }
}

// ---------------- main fused kernel: 1 wave = 16 pixels ----------------
__global__ __launch_bounds__(64, 2) void fused_kernel(
    const u16*  __restrict__ nrmb, const float* __restrict__ fmu,
    const u16*  __restrict__ wsb,
    const float* __restrict__ ctx_g, const float* __restrict__ ctx_b,
    const float* __restrict__ qb, const float* __restrict__ kb,
    const float* __restrict__ vb, const float* __restrict__ ob,
    const float* __restrict__ f1b, const float* __restrict__ f2b,
    const float* __restrict__ o1b, const float* __restrict__ o2w,
    const float* __restrict__ o2b,
    float* __restrict__ out)
{
    const int lane = threadIdx.x;
    const int cidx = lane & 15, quad = lane >> 4;
    const int n0 = blockIdx.x * 16;
    const int b  = n0 / (HU_ * WU_);
    const int rem = n0 - b * (HU_ * WU_);
    const int hu  = rem / WU_;
    const int wu0 = rem - hu * WU_;

    __shared__ u16  arena[8 * SLOT];   // 34816 B
    __shared__ float s_at[256];        // scores/attn; tail: s_rs
    u16* sH = arena;                   // fc1 acts, rows stride 520 (slots 0..3)
    float* bufQ = (float*)(arena + 6 * SLOT);   // q/xf f32, rows stride 136 (slots 6,7)
    float* s_rs = s_at;

    // residual x: row p = 4*quad+r, ch = 16*nt+cidx
    float xacc[8][4];
#pragma unroll
    for (int nt = 0; nt < 8; ++nt) {
        int ch = 16 * nt + cidx;
        const float* p = fmu + ((size_t)(b * C_ + ch) * HU_ + hu) * WU_ + wu0 + 4 * quad;
#pragma unroll
        for (int r = 0; r < 4; ++r) xacc[nt][r] = p[r];
    }

    const float slopes[4] = {0.451801007f, 0.204124145f, 0.092223264f, 0.041666668f};
    const int ry0 = min(hu >> 1, HD_ - 1);
    const int ry1 = min((hu >> 1) + 1, HD_ - 1);
    const float dyv0 = -(float)abs(hu - 2 * ry0);
    const float dyv1 = -(float)abs(hu - 2 * ry1);

    // per-lane ctx source row (fixed across layers): p=4*mt+(cidx>>2), k2=cidx&3
    const int k2l = cidx & 3;
    const int ryl = (k2l >> 1) ? ry1 : ry0;
    size_t csrc_base[4];
#pragma unroll
    for (int mt = 0; mt < 4; ++mt) {
        int p = 4 * mt + (cidx >> 2);
        int rxv = min(((wu0 + p) >> 1) + (k2l & 1), WD_ - 1);
        csrc_base[mt] = ((size_t)((b * HD_ + ryl) * WD_ + rxv)) * 128 + 32 * quad;
    }

#pragma unroll 1
    for (int ly = 0; ly < 2; ++ly) {
        const u16* Wq = wsb + OFF_Q  + ly * 16384;
        const u16* Wk = wsb + OFF_K  + ly * 16384;
        const u16* Wv = wsb + OFF_V  + ly * 16384;
        const u16* Wo = wsb + OFF_O  + ly * 16384;
        const u16* W1 = wsb + OFF_F1 + ly * 65536;
        const u16* W2 = wsb + OFF_F2 + ly * 65536;
        const float* gv  = ctx_g + ly * C_;
        const float* bv  = ctx_b + ly * C_;

        // ---- build xn tile (slot 4) + cn tiles (slots 0..3) ----
        {
            float mo[4], io[4];
#pragma unroll
            for (int r = 0; r < 4; ++r) {
                float s = 0.f, ss = 0.f;
#pragma unroll
                for (int nt = 0; nt < 8; ++nt) { float v = xacc[nt][r]; s += v; ss += v * v; }
#pragma unroll
                for (int m = 1; m <= 8; m <<= 1) { s += __shfl_xor(s, m, 64); ss += __shfl_xor(ss, m, 64); }
                float mn = s * (1.f / 128.f);
                mo[r] = mn; io[r] = rsqrtf(ss * (1.f / 128.f) - mn * mn + 1e-6f);
            }
#pragma unroll
            for (int nt = 0; nt < 8; ++nt)
#pragma unroll
                for (int r = 0; r < 4; ++r)
                    arena[4 * SLOT + (4 * quad + r) * 136 + 16 * nt + cidx] =
                        f2bf((xacc[nt][r] - mo[r]) * io[r]);
        }
#pragma unroll 1
        for (int mt = 0; mt < 4; ++mt) {
            const u16* csrc = nrmb + csrc_base[mt];
            u16* drow = arena + mt * SLOT + cidx * 136 + 32 * quad;
#pragma unroll
            for (int t = 0; t < 4; ++t) {
                s8v raw = *(const s8v*)(csrc + 8 * t);
                float4 g0 = *(const float4*)&gv[32 * quad + 8 * t];
                float4 g1 = *(const float4*)&gv[32 * quad + 8 * t + 4];
                float4 b0 = *(const float4*)&bv[32 * quad + 8 * t];
                float4 b1 = *(const float4*)&bv[32 * quad + 8 * t + 4];
                s8v o;
                o[0] = (short)f2bf(fmaf(bfu((u16)raw[0]), g0.x, b0.x));
                o[1] = (short)f2bf(fmaf(bfu((u16)raw[1]), g0.y, b0.y));
                o[2] = (short)f2bf(fmaf(bfu((u16)raw[2]), g0.z, b0.z));
                o[3] = (short)f2bf(fmaf(bfu((u16)raw[3]), g0.w, b0.w));
                o[4] = (short)f2bf(fmaf(bfu((u16)raw[4]), g1.x, b1.x));
                o[5] = (short)f2bf(fmaf(bfu((u16)raw[5]), g1.y, b1.y));
                o[6] = (short)f2bf(fmaf(bfu((u16)raw[6]), g1.z, b1.z));
                o[7] = (short)f2bf(fmaf(bfu((u16)raw[7]), g1.w, b1.w));
                *(s8v*)(drow + 8 * t) = o;
            }
        }
        __syncthreads();

        // ---- q = xn @ Wq + qb -> bufQ (f32) ----
        {
            f4v qa[8];
#pragma unroll
            for (int nt = 0; nt < 8; ++nt) {
                float bvv = qb[ly * C_ + 16 * nt + cidx];
                f4v t = {bvv, bvv, bvv, bvv}; qa[nt] = t;
            }
            for (int kt = 0; kt < 4; ++kt) {
                s8v a = *(const s8v*)(arena + 4 * SLOT + cidx * 136 + kt * 32 + 8 * quad);
#pragma unroll
                for (int nt = 0; nt < 8; ++nt) {
                    s8v w = *(const s8v*)(Wq + ((size_t)((kt * 8 + nt) * 64 + lane)) * 8);
                    qa[nt] = __builtin_amdgcn_mfma_f32_16x16x32_bf16(a, w, qa[nt], 0, 0, 0);
                }
            }
#pragma unroll
            for (int nt = 0; nt < 8; ++nt)
#pragma unroll
                for (int r = 0; r < 4; ++r)
                    bufQ[(4 * quad + r) * 136 + 16 * nt + cidx] = qa[nt][r];
        }
        __syncthreads();

        // ---- preload cn A-frags (held through k and v) ----
        s8v a_cn[4][4];
#pragma unroll
        for (int kt = 0; kt < 4; ++kt)
#pragma unroll
            for (int mt = 0; mt < 4; ++mt)
                a_cn[kt][mt] = *(const s8v*)(arena + mt * SLOT + cidx * 136 + kt * 32 + 8 * quad);

        // ---- k GEMM (frag-once), fused raw scores -> s_at ----
#pragma unroll 1
        for (int h = 0; h < 4; ++h) {
            f4v ka[2][4];
#pragma unroll
            for (int ntp = 0; ntp < 2; ++ntp) {
                float kbb = kb[ly * C_ + 16 * (2 * h + ntp) + cidx];
#pragma unroll
                for (int mt = 0; mt < 4; ++mt) { f4v t = {kbb, kbb, kbb, kbb}; ka[ntp][mt] = t; }
            }
#pragma unroll
            for (int kt = 0; kt < 4; ++kt)
#pragma unroll
                for (int ntp = 0; ntp < 2; ++ntp) {
                    int nt = 2 * h + ntp;
                    s8v w = *(const s8v*)(Wk + ((size_t)((kt * 8 + nt) * 64 + lane)) * 8);
#pragma unroll
                    for (int mt = 0; mt < 4; ++mt)
                        ka[ntp][mt] = __builtin_amdgcn_mfma_f32_16x16x32_bf16(a_cn[kt][mt], w, ka[ntp][mt], 0, 0, 0);
                }
            float part[4][4];
#pragma unroll
            for (int mt = 0; mt < 4; ++mt)
#pragma unroll
                for (int r = 0; r < 4; ++r) part[mt][r] = 0.f;
#pragma unroll
            for (int ntp = 0; ntp < 2; ++ntp)
#pragma unroll
                for (int mt = 0; mt < 4; ++mt) {
                    float qv = bufQ[(4 * mt + quad) * 136 + 16 * (2 * h + ntp) + cidx];
#pragma unroll
                    for (int r = 0; r < 4; ++r) part[mt][r] = fmaf(qv, ka[ntp][mt][r], part[mt][r]);
                }
#pragma unroll
            for (int mt = 0; mt < 4; ++mt)
#pragma unroll
                for (int r = 0; r < 4; ++r) {
#pragma unroll
                    for (int m = 1; m <= 8; m <<= 1) part[mt][r] += __shfl_xor(part[mt][r], m, 64);
                }
            if (cidx == 0) {
#pragma unroll
                for (int mt = 0; mt < 4; ++mt) {
                    float4 t = {part[mt][0], part[mt][1], part[mt][2], part[mt][3]};
                    *(float4*)&s_at[(4 * mt + quad) * 16 + 4 * h] = t;
                }
            }
        }
        __syncthreads();

        // ---- softmax (in place, all lanes: p=lane>>2, h=lane&3) ----
        {
            int p = lane >> 2, h = lane & 3;
            float4 sc = *(float4*)&s_at[p * 16 + 4 * h];
            int pw = wu0 + p;
            float sim[4] = {sc.x, sc.y, sc.z, sc.w};
#pragma unroll
            for (int r = 0; r < 4; ++r) {
                int rxv = min((pw >> 1) + (r & 1), WD_ - 1);
                float cd = ((r >> 1) ? dyv1 : dyv0) - (float)abs(pw - 2 * rxv);
                sim[r] = sim[r] * 0.17677669529663687f + slopes[h] * cd;
            }
            float mx = fmaxf(fmaxf(sim[0], sim[1]), fmaxf(sim[2], sim[3]));
            float e0 = expf(sim[0] - mx), e1 = expf(sim[1] - mx);
            float e2 = expf(sim[2] - mx), e3 = expf(sim[3] - mx);
            float si = 1.f / (e0 + e1 + e2 + e3);
            float4 at = {e0 * si, e1 * si, e2 * si, e3 * si};
            __syncthreads();
            *(float4*)&s_at[p * 16 + 4 * h] = at;
        }
        __syncthreads();

        // ---- v GEMM (frag-once) fused o=attn@v -> oT (slot 5) ----
#pragma unroll 1
        for (int nt = 0; nt < 8; ++nt) {
            f4v va[4];
            float vbb = vb[ly * C_ + 16 * nt + cidx];
#pragma unroll
            for (int mt = 0; mt < 4; ++mt) { f4v t = {vbb, vbb, vbb, vbb}; va[mt] = t; }
#pragma unroll
            for (int kt = 0; kt < 4; ++kt) {
                s8v w = *(const s8v*)(Wv + ((size_t)((kt * 8 + nt) * 64 + lane)) * 8);
#pragma unroll
                for (int mt = 0; mt < 4; ++mt)
                    va[mt] = __builtin_amdgcn_mfma_f32_16x16x32_bf16(a_cn[kt][mt], w, va[mt], 0, 0, 0);
            }
            int h = nt >> 1;
#pragma unroll
            for (int mt = 0; mt < 4; ++mt) {
                float4 at = *(float4*)&s_at[(4 * mt + quad) * 16 + 4 * h];
                float ov = at.x * va[mt][0] + at.y * va[mt][1] + at.z * va[mt][2] + at.w * va[mt][3];
                arena[5 * SLOT + (4 * mt + quad) * 136 + 16 * nt + cidx] = f2bf(ov);
            }
        }
        __syncthreads();

        // ---- x += o @ Wo + ob ----
        {
            f4v oa[8];
#pragma unroll
            for (int nt = 0; nt < 8; ++nt) {
                float bvv = ob[ly * C_ + 16 * nt + cidx];
                f4v t = {bvv, bvv, bvv, bvv}; oa[nt] = t;
            }
            for (int kt = 0; kt < 4; ++kt) {
                s8v a = *(const s8v*)(arena + 5 * SLOT + cidx * 136 + kt * 32 + 8 * quad);
#pragma unroll
                for (int nt = 0; nt < 8; ++nt) {
                    s8v w = *(const s8v*)(Wo + ((size_t)((kt * 8 + nt) * 64 + lane)) * 8);
                    oa[nt] = __builtin_amdgcn_mfma_f32_16x16x32_bf16(a, w, oa[nt], 0, 0, 0);
                }
            }
#pragma unroll
            for (int nt = 0; nt < 8; ++nt)
#pragma unroll
                for (int r = 0; r < 4; ++r) xacc[nt][r] += oa[nt][r];
        }

        // ---- hn = LN(x) -> slot 4 ----
        {
            float mo[4], io[4];
#pragma unroll
            for (int r = 0; r < 4; ++r) {
                float s = 0.f, ss = 0.f;
#pragma unroll
                for (int nt = 0; nt < 8; ++nt) { float v = xacc[nt][r]; s += v; ss += v * v; }
#pragma unroll
                for (int m = 1; m <= 8; m <<= 1) { s += __shfl_xor(s, m, 64); ss += __shfl_xor(ss, m, 64); }
                float mn = s * (1.f / 128.f);
                mo[r] = mn; io[r] = rsqrtf(ss * (1.f / 128.f) - mn * mn + 1e-6f);
            }
            __syncthreads();
#pragma unroll
            for (int nt = 0; nt < 8; ++nt)
#pragma unroll
                for (int r = 0; r < 4; ++r)
                    arena[4 * SLOT + (4 * quad + r) * 136 + 16 * nt + cidx] =
                        f2bf((xacc[nt][r] - mo[r]) * io[r]);
        }
        __syncthreads();

        // ---- fc1 + gelu_tanh -> sH ----
#pragma unroll 1
        for (int half = 0; half < 2; ++half) {
            f4v fa[16];
#pragma unroll
            for (int nt = 0; nt < 16; ++nt) {
                float bvv = f1b[ly * 512 + 16 * (half * 16 + nt) + cidx];
                f4v t = {bvv, bvv, bvv, bvv}; fa[nt] = t;
            }
            for (int kt = 0; kt < 4; ++kt) {
                s8v a = *(const s8v*)(arena + 4 * SLOT + cidx * 136 + kt * 32 + 8 * quad);
#pragma unroll
                for (int nt = 0; nt < 16; ++nt) {
                    int ntg = half * 16 + nt;
                    s8v w = *(const s8v*)(W1 + ((size_t)((kt * 32 + ntg) * 64 + lane)) * 8);
                    fa[nt] = __builtin_amdgcn_mfma_f32_16x16x32_bf16(a, w, fa[nt], 0, 0, 0);
                }
            }
#pragma unroll
            for (int nt = 0; nt < 16; ++nt)
#pragma unroll
                for (int r = 0; r < 4; ++r)
                    sH[(4 * quad + r) * 520 + 16 * (half * 16 + nt) + cidx] =
                        f2bf(gelu_tanh(fa[nt][r]));
        }
        __syncthreads();

        // ---- x += act @ W2 + f2b ----
        {
            f4v ga[8];
#pragma unroll
            for (int nt = 0; nt < 8; ++nt) {
                float bvv = f2b[ly * C_ + 16 * nt + cidx];
                f4v t = {bvv, bvv, bvv, bvv}; ga[nt] = t;
            }
            for (int kt = 0; kt < 16; ++kt) {
                s8v a = *(const s8v*)(sH + cidx * 520 + kt * 32 + 8 * quad);
#pragma unroll
                for (int nt = 0; nt < 8; ++nt) {
                    s8v w = *(const s8v*)(W2 + ((size_t)((kt * 8 + nt) * 64 + lane)) * 8);
                    ga[nt] = __builtin_amdgcn_mfma_f32_16x16x32_bf16(a, w, ga[nt], 0, 0, 0);
                }
            }
#pragma unroll
            for (int nt = 0; nt < 8; ++nt)
#pragma unroll
                for (int r = 0; r < 4; ++r) xacc[nt][r] += ga[nt][r];
        }
        __syncthreads();
    } // layer loop

    // ---- head: xf = LN(x) -> bufQ (f32) ----
    {
        float mo[4], io[4];
#pragma unroll
        for (int r = 0; r < 4; ++r) {
            float s = 0.f, ss = 0.f;
#pragma unroll
            for (int nt = 0; nt < 8; ++nt) { float v = xacc[nt][r]; s += v; ss += v * v; }
#pragma unroll
            for (int m = 1; m <= 8; m <<= 1) { s += __shfl_xor(s, m, 64); ss += __shfl_xor(ss, m, 64); }
            float mn = s * (1.f / 128.f);
            mo[r] = mn; io[r] = rsqrtf(ss * (1.f / 128.f) - mn * mn + 1e-6f);
        }
#pragma unroll
        for (int nt = 0; nt < 8; ++nt)
#pragma unroll
            for (int r = 0; r < 4; ++r)
                bufQ[(4 * quad + r) * 136 + 16 * nt + cidx] = (xacc[nt][r] - mo[r]) * io[r];
    }
    __syncthreads();

    const u16* W1h = wsb + OFF_O1;
#pragma unroll 1
    for (int pr = 0; pr < 2; ++pr) {    // mt pair: mt = 2*pr+pp
        // build 6 tiles: seg0 slots 0,1 (xf); seg1 slots 2,3 (cf); seg2 slots 4,5 (xf-cf)
#pragma unroll
        for (int pp = 0; pp < 2; ++pp) {
            int mt = 2 * pr + pp;
            int p  = 4 * mt + (cidx >> 2);
            const u16* csrc = nrmb + csrc_base[mt];
#pragma unroll
            for (int t = 0; t < 4; ++t) {
                s8v craw = *(const s8v*)(csrc + 8 * t);
                float4 xa = *(float4*)&bufQ[p * 136 + 32 * quad + 8 * t];
                float4 xb = *(float4*)&bufQ[p * 136 + 32 * quad + 8 * t + 4];
                float xv[8] = {xa.x, xa.y, xa.z, xa.w, xb.x, xb.y, xb.z, xb.w};
                s8v xo, dv;
#pragma unroll
                for (int j = 0; j < 8; ++j) {
                    xo[j] = (short)f2bf(xv[j]);
                    dv[j] = (short)f2bf(xv[j] - bfu((u16)craw[j]));
                }
                int ro = cidx * 136 + 32 * quad + 8 * t;
                *(s8v*)(arena + pp * SLOT + ro)       = xo;
                *(s8v*)(arena + (2 + pp) * SLOT + ro) = craw;
                *(s8v*)(arena + (4 + pp) * SLOT + ro) = dv;
            }
        }
        __syncthreads();

        float part[2][4];
#pragma unroll
        for (int pp = 0; pp < 2; ++pp)
#pragma unroll
            for (int r = 0; r < 4; ++r) part[pp][r] = 0.f;

#pragma unroll 1
        for (int ntc = 0; ntc < 4; ++ntc) {
            f4v hacc[6][2];
#pragma unroll
            for (int ntl = 0; ntl < 6; ++ntl) {
                float hb = o1b[16 * (6 * ntc + ntl) + cidx];
#pragma unroll
                for (int pp = 0; pp < 2; ++pp) { f4v t = {hb, hb, hb, hb}; hacc[ntl][pp] = t; }
            }
#pragma unroll 1
            for (int kt = 0; kt < 12; ++kt) {
                int seg = kt >> 2, kk = kt & 3;
                s8v a[2];
#pragma unroll
                for (int pp = 0; pp < 2; ++pp)
                    a[pp] = *(const s8v*)(arena + (seg * 2 + pp) * SLOT + cidx * 136 + kk * 32 + 8 * quad);
#pragma unroll
                for (int ntl = 0; ntl < 6; ++ntl) {
                    int nt = 6 * ntc + ntl;
                    s8v w = *(const s8v*)(W1h + ((size_t)(kt * 24 + nt) * 64 + lane)) * 0 +
                            *(const s8v*)(W1h + ((size_t)(kt * 24 + nt) * 64 + lane) * 8);
#pragma unroll
                    for (int pp = 0; pp < 2; ++pp)
                        hacc[ntl][pp] = __builtin_amdgcn_mfma_f32_16x16x32_bf16(a[pp], w, hacc[ntl][pp], 0, 0, 0);
                }
            }
#pragma unroll
            for (int ntl = 0; ntl < 6; ++ntl) {
                float w2v = o2w[16 * (6 * ntc + ntl) + cidx];
#pragma unroll
                for (int pp = 0; pp < 2; ++pp)
#pragma unroll
                    for (int r = 0; r < 4; ++r)
                        part[pp][r] = fmaf(gelu_erf(hacc[ntl][pp][r]), w2v, part[pp][r]);
            }
        }
#pragma unroll
        for (int pp = 0; pp < 2; ++pp)
#pragma unroll
            for (int r = 0; r < 4; ++r) {
#pragma unroll
                for (int m = 1; m <= 8; m <<= 1) part[pp][r] += __shfl_xor(part[pp][r], m, 64);
                part[pp][r] += o2b[0];
            }
        if (cidx == 0) {
#pragma unroll
            for (int pp = 0; pp < 2; ++pp) {
                int p = 4 * (2 * pr + pp) + quad;
                float4 t = {part[pp][0], part[pp][1], part[pp][2], part[pp][3]};
                *(float4*)&s_rs[p * 4] = t;
            }
        }
        __syncthreads();
    }

    // final softmax over K2 + store
    if (lane < 16) {
        int p = lane;
        float4 vv = *(float4*)&s_rs[4 * p];
        float mx = fmaxf(fmaxf(vv.x, vv.y), fmaxf(vv.z, vv.w));
        float e0 = expf(vv.x - mx), e1 = expf(vv.y - mx);
        float e2 = expf(vv.z - mx), e3 = expf(vv.w - mx);
        float si = 1.f / (e0 + e1 + e2 + e3);
        size_t base = ((size_t)(b * 4) * HU_ + hu) * WU_ + wu0 + p;
        out[base]                          = e0 * si;
        out[base + (size_t)HU_ * WU_]      = e1 * si;
        out[base + (size_t)2 * HU_ * WU_]  = e2 * si;
        out[base + (size_t)3 * HU_ * WU_]  = e3 * si;
    }
}

extern "C" void kernel_launch(void* const* d_in, const int* in_sizes, int n_in,
                              void* d_out, int out_size, void* d_ws, size_t ws_size,
                              hipStream_t stream) {
    const float* feat_map    = (const float*)d_in[0];
    const float* feat_map_up = (const float*)d_in[1];
    const float* ctx_ln_b    = (const float*)d_in[2];
    const float* q_w  = (const float*)d_in[3];
    const float* q_b  = (const float*)d_in[4];
    const float* k_w  = (const float*)d_in[5];
    const float* k_b  = (const float*)d_in[6];
    const float* v_w  = (const float*)d_in[7];
    const float* v_b  = (const float*)d_in[8];
    const float* o_w  = (const float*)d_in[9];
    const float* o_b  = (const float*)d_in[10];
    const float* fc1_w = (const float*)d_in[11];
    const float* fc1_b = (const float*)d_in[12];
    const float* fc2_w = (const float*)d_in[13];
    const float* fc2_b = (const float*)d_in[14];
    const float* out1_w = (const float*)d_in[15];
    const float* out1_b = (const float*)d_in[16];
    const float* out2_w = (const float*)d_in[17];
    const float* out2_b = (const float*)d_in[18];
    const float* ctx_ln_g = (const float*)d_in[19];
    float* out = (float*)d_out;
    u16* ws = (u16*)d_ws;

    for (int l = 0; l < 2; ++l) {
        swz_kernel<<<8, 256, 0, stream>>>(q_w + l * 16384, ws + OFF_Q + l * 16384, 4, 8, 128);
        swz_kernel<<<8, 256, 0, stream>>>(k_w + l * 16384, ws + OFF_K + l * 16384, 4, 8, 128);
        swz_kernel<<<8, 256, 0, stream>>>(v_w + l * 16384, ws + OFF_V + l * 16384, 4, 8, 128);
        swz_kernel<<<8, 256, 0, stream>>>(o_w + l * 16384, ws + OFF_O + l * 16384, 4, 8, 128);
        swz_kernel<<<32, 256, 0, stream>>>(fc1_w + l * 65536, ws + OFF_F1 + l * 65536, 4, 32, 512);
        swz_kernel<<<32, 256, 0, stream>>>(fc2_w + l * 65536, ws + OFF_F2 + l * 65536, 16, 8, 128);
    }
    swz_kernel<<<72, 256, 0, stream>>>(out1_w, ws + OFF_O1, 12, 24, 384);
    norm_kernel<<<128, 256, 0, stream>>>(feat_map, ws + OFF_NRM);

    fused_kernel<<<3072, 64, 0, stream>>>(
        ws + OFF_NRM, feat_map_up, ws, ctx_ln_g, ctx_ln_b,
        q_b, k_b, v_b, o_b, fc1_b, fc2_b,
        out1_b, out2_w, out2_b, out);
}